// Round 2
// baseline (50.678 us; speedup 1.0000x reference)
//
#include <hip/hip_runtime.h>

// Problem constants (from reference): B=32, K=8, H=240, W=320
constexpr int B_  = 32;
constexpr int K_  = 8;
constexpr int H_  = 240;
constexpr int W_  = 320;
constexpr int HW  = H_ * W_;     // 76800
constexpr int NQ  = HW / 4;      // 19200 float4 quads per plane
constexpr int TPB = 256;         // threads per block
constexpr int BPB = NQ / TPB;    // 75 blocks per batch -> exactly 1 quad/thread

// loss = 0.5 * sum_b (1/numpts[b]) * sum_{i,h,w} err^2
// pred[b,i,hw] = sum_k m[b,k,hw] * ( R[b,k,i,:]·p[b,:,hw] + t[b,k,i] )
__global__ __launch_bounds__(TPB)
void w3d_loss_kernel(const float* __restrict__ pts,
                     const float* __restrict__ masks,
                     const float* __restrict__ tfms,
                     const float* __restrict__ tgt,
                     const float* __restrict__ numpts,
                     float* __restrict__ out)
{
    const int b = blockIdx.x / BPB;
    const int q = (blockIdx.x % BPB) * TPB + (int)threadIdx.x;  // < NQ by construction

    // Stage this batch's K transforms (8 * 12 floats) in LDS.
    __shared__ float stfm[K_ * 12];
    if (threadIdx.x < K_ * 12)
        stfm[threadIdx.x] = tfms[(size_t)b * K_ * 12 + threadIdx.x];
    __syncthreads();

    const float4* Px = (const float4*)(pts + (size_t)b * 3 * HW);
    const float4* Py = Px + NQ;
    const float4* Pz = Py + NQ;
    const float4* Tx = (const float4*)(tgt + (size_t)b * 3 * HW);
    const float4* Ty = Tx + NQ;
    const float4* Tz = Ty + NQ;
    const float4* Mb = (const float4*)(masks + (size_t)b * K_ * HW);

    // Issue all 6 point/target loads up front (independent, in flight together).
    const float4 p4x = Px[q], p4y = Py[q], p4z = Pz[q];
    const float4 t4x = Tx[q], t4y = Ty[q], t4z = Tz[q];

    const float px[4] = {p4x.x, p4x.y, p4x.z, p4x.w};
    const float py[4] = {p4y.x, p4y.y, p4y.z, p4y.w};
    const float pz[4] = {p4z.x, p4z.y, p4z.z, p4z.w};

    float prx[4] = {0.f, 0.f, 0.f, 0.f};
    float pry[4] = {0.f, 0.f, 0.f, 0.f};
    float prz[4] = {0.f, 0.f, 0.f, 0.f};

    #pragma unroll
    for (int k = 0; k < K_; ++k) {
        const float4 m4 = Mb[(size_t)k * NQ + q];
        const float m[4] = {m4.x, m4.y, m4.z, m4.w};
        const float* f = &stfm[k * 12];
        // rows of [R|t]: f[0..3] -> x out, f[4..7] -> y out, f[8..11] -> z out
        #pragma unroll
        for (int l = 0; l < 4; ++l) {
            const float vx = fmaf(f[0], px[l], fmaf(f[1], py[l], fmaf(f[2], pz[l], f[3])));
            const float vy = fmaf(f[4], px[l], fmaf(f[5], py[l], fmaf(f[6], pz[l], f[7])));
            const float vz = fmaf(f[8], px[l], fmaf(f[9], py[l], fmaf(f[10], pz[l], f[11])));
            prx[l] = fmaf(m[l], vx, prx[l]);
            pry[l] = fmaf(m[l], vy, pry[l]);
            prz[l] = fmaf(m[l], vz, prz[l]);
        }
    }

    const float ttx[4] = {t4x.x, t4x.y, t4x.z, t4x.w};
    const float tty[4] = {t4y.x, t4y.y, t4y.z, t4y.w};
    const float ttz[4] = {t4z.x, t4z.y, t4z.z, t4z.w};

    float acc = 0.0f;
    #pragma unroll
    for (int l = 0; l < 4; ++l) {
        const float ex = prx[l] - ttx[l];
        const float ey = pry[l] - tty[l];
        const float ez = prz[l] - ttz[l];
        acc = fmaf(ex, ex, acc);
        acc = fmaf(ey, ey, acc);
        acc = fmaf(ez, ez, acc);
    }

    // Wave-64 butterfly reduce
    #pragma unroll
    for (int off = 32; off > 0; off >>= 1)
        acc += __shfl_down(acc, off, 64);

    __shared__ float wsum[TPB / 64];
    const int wid  = threadIdx.x >> 6;
    const int lane = threadIdx.x & 63;
    if (lane == 0) wsum[wid] = acc;
    __syncthreads();

    if (threadIdx.x == 0) {
        float s = 0.f;
        #pragma unroll
        for (int w = 0; w < TPB / 64; ++w) s += wsum[w];
        atomicAdd(out, 0.5f * s / numpts[b]);
    }
}

extern "C" void kernel_launch(void* const* d_in, const int* in_sizes, int n_in,
                              void* d_out, int out_size, void* d_ws, size_t ws_size,
                              hipStream_t stream)
{
    const float* pts    = (const float*)d_in[0];
    const float* masks  = (const float*)d_in[1];
    const float* tfms   = (const float*)d_in[2];
    const float* tgt    = (const float*)d_in[3];
    const float* numpts = (const float*)d_in[4];
    float* out = (float*)d_out;

    // d_out is poisoned (0xAA) before timing and never re-poisoned between
    // replays; zero it every call so the atomics accumulate from 0.
    hipMemsetAsync(out, 0, sizeof(float) * out_size, stream);

    dim3 grid(B_ * BPB);
    dim3 block(TPB);
    w3d_loss_kernel<<<grid, block, 0, stream>>>(pts, masks, tfms, tgt, numpts, out);
}

// Round 3
// 37.454 us; speedup vs baseline: 1.3531x; 1.3531x over previous
//
#include <hip/hip_runtime.h>

// Problem constants (from reference): B=32, K=8, H=240, W=320
constexpr int B_  = 32;
constexpr int K_  = 8;
constexpr int H_  = 240;
constexpr int W_  = 320;
constexpr int HW  = H_ * W_;          // 76800
constexpr int NQ  = HW / 4;           // 19200 float4 quads per plane
constexpr int TPB = 256;              // threads per block
constexpr int NPT = 3;                // quads per thread
constexpr int BPB = NQ / (TPB * NPT); // 25 blocks per batch -> grid 800

// One iteration's worth of streaming data: 14 float4 = 56 VGPRs.
// Two of these live at once (double-buffer) = 112 VGPRs of load data.
struct Frag {
    float4 px, py, pz, tx, ty, tz;
    float4 m[K_];
};

__device__ __forceinline__ void load_frag(Frag& F,
                                          const float4* __restrict__ Px,
                                          const float4* __restrict__ Py,
                                          const float4* __restrict__ Pz,
                                          const float4* __restrict__ Tx,
                                          const float4* __restrict__ Ty,
                                          const float4* __restrict__ Tz,
                                          const float4* __restrict__ Mb,
                                          int q)
{
    // 14 independent dwordx4 loads — keep them all in flight together.
    F.px = Px[q]; F.py = Py[q]; F.pz = Pz[q];
    F.tx = Tx[q]; F.ty = Ty[q]; F.tz = Tz[q];
    #pragma unroll
    for (int k = 0; k < K_; ++k) F.m[k] = Mb[(size_t)k * NQ + q];
}

// tf points at this batch's 8x12 transform block in GLOBAL memory; the
// address is wave-uniform so these compile to s_load (scalar pipe).
__device__ __forceinline__ void accum(const Frag& F, const float* __restrict__ tf,
                                      float& acc)
{
    const float px[4] = {F.px.x, F.px.y, F.px.z, F.px.w};
    const float py[4] = {F.py.x, F.py.y, F.py.z, F.py.w};
    const float pz[4] = {F.pz.x, F.pz.y, F.pz.z, F.pz.w};

    float prx[4] = {0.f, 0.f, 0.f, 0.f};
    float pry[4] = {0.f, 0.f, 0.f, 0.f};
    float prz[4] = {0.f, 0.f, 0.f, 0.f};

    #pragma unroll
    for (int k = 0; k < K_; ++k) {
        const float f0 = tf[k*12+0], f1 = tf[k*12+1], f2  = tf[k*12+2],  f3  = tf[k*12+3];
        const float f4 = tf[k*12+4], f5 = tf[k*12+5], f6  = tf[k*12+6],  f7  = tf[k*12+7];
        const float f8 = tf[k*12+8], f9 = tf[k*12+9], f10 = tf[k*12+10], f11 = tf[k*12+11];
        const float m[4] = {F.m[k].x, F.m[k].y, F.m[k].z, F.m[k].w};
        #pragma unroll
        for (int l = 0; l < 4; ++l) {
            const float vx = fmaf(f0, px[l], fmaf(f1, py[l], fmaf(f2,  pz[l], f3)));
            const float vy = fmaf(f4, px[l], fmaf(f5, py[l], fmaf(f6,  pz[l], f7)));
            const float vz = fmaf(f8, px[l], fmaf(f9, py[l], fmaf(f10, pz[l], f11)));
            prx[l] = fmaf(m[l], vx, prx[l]);
            pry[l] = fmaf(m[l], vy, pry[l]);
            prz[l] = fmaf(m[l], vz, prz[l]);
        }
    }

    const float tx[4] = {F.tx.x, F.tx.y, F.tx.z, F.tx.w};
    const float ty[4] = {F.ty.x, F.ty.y, F.ty.z, F.ty.w};
    const float tz[4] = {F.tz.x, F.tz.y, F.tz.z, F.tz.w};
    #pragma unroll
    for (int l = 0; l < 4; ++l) {
        const float ex = prx[l] - tx[l];
        const float ey = pry[l] - ty[l];
        const float ez = prz[l] - tz[l];
        acc = fmaf(ex, ex, acc);
        acc = fmaf(ey, ey, acc);
        acc = fmaf(ez, ez, acc);
    }
}

__global__ __launch_bounds__(TPB, 2)
void w3d_loss_kernel(const float* __restrict__ pts,
                     const float* __restrict__ masks,
                     const float* __restrict__ tfms,
                     const float* __restrict__ tgt,
                     const float* __restrict__ numpts,
                     float* __restrict__ out)
{
    const int b   = blockIdx.x / BPB;
    const int blk = blockIdx.x % BPB;
    const int q0  = blk * (TPB * NPT) + (int)threadIdx.x;

    const float4* Px = (const float4*)(pts + (size_t)b * 3 * HW);
    const float4* Py = Px + NQ;
    const float4* Pz = Py + NQ;
    const float4* Tx = (const float4*)(tgt + (size_t)b * 3 * HW);
    const float4* Ty = Tx + NQ;
    const float4* Tz = Ty + NQ;
    const float4* Mb = (const float4*)(masks + (size_t)b * K_ * HW);
    const float*  tf = tfms + (size_t)b * K_ * 12;   // wave-uniform -> s_load

    float acc = 0.0f;

    // Software pipeline, fully unrolled (NPT=3): always one Frag in flight.
    Frag A, Bf;
    load_frag(A,  Px, Py, Pz, Tx, Ty, Tz, Mb, q0);
    load_frag(Bf, Px, Py, Pz, Tx, Ty, Tz, Mb, q0 + TPB);
    accum(A, tf, acc);
    load_frag(A,  Px, Py, Pz, Tx, Ty, Tz, Mb, q0 + 2 * TPB);
    accum(Bf, tf, acc);
    accum(A, tf, acc);

    // Wave-64 butterfly reduce
    #pragma unroll
    for (int off = 32; off > 0; off >>= 1)
        acc += __shfl_down(acc, off, 64);

    __shared__ float wsum[TPB / 64];
    const int wid  = threadIdx.x >> 6;
    const int lane = threadIdx.x & 63;
    if (lane == 0) wsum[wid] = acc;
    __syncthreads();

    if (threadIdx.x == 0) {
        float s = 0.f;
        #pragma unroll
        for (int w = 0; w < TPB / 64; ++w) s += wsum[w];
        atomicAdd(out, 0.5f * s / numpts[b]);
    }
}

extern "C" void kernel_launch(void* const* d_in, const int* in_sizes, int n_in,
                              void* d_out, int out_size, void* d_ws, size_t ws_size,
                              hipStream_t stream)
{
    const float* pts    = (const float*)d_in[0];
    const float* masks  = (const float*)d_in[1];
    const float* tfms   = (const float*)d_in[2];
    const float* tgt    = (const float*)d_in[3];
    const float* numpts = (const float*)d_in[4];
    float* out = (float*)d_out;

    // d_out is poisoned (0xAA) before timing and never re-poisoned between
    // replays; zero it every call so the atomics accumulate from 0.
    hipMemsetAsync(out, 0, sizeof(float) * out_size, stream);

    dim3 grid(B_ * BPB);
    dim3 block(TPB);
    w3d_loss_kernel<<<grid, block, 0, stream>>>(pts, masks, tfms, tgt, numpts, out);
}